// Round 7
// baseline (874.415 us; speedup 1.0000x reference)
//
#include <hip/hip_runtime.h>

#define H    128
#define NMQ  50000
#define NSQ  50000
#define NE   600000
#define NEL  200000
#define FIN  768
#define NLAYERS 4

typedef __attribute__((ext_vector_type(8))) short bf16x8;
typedef __attribute__((ext_vector_type(4))) float f32x4;

__device__ inline ushort f2b(float f) {
  unsigned u = __float_as_uint(f);
  u = (u + 0x7FFFu + ((u >> 16) & 1u)) >> 16;
  return (ushort)u;
}
__device__ inline float b2f(ushort h) { return __uint_as_float((unsigned)h << 16); }

// ---------------- generic fp32 -> bf16 convert (n divisible by 4) ----------------
__global__ void cvt_bf16(const float* __restrict__ in, ushort* __restrict__ out, int n4) {
  int i = blockIdx.x * blockDim.x + threadIdx.x;
  if (i >= n4) return;
  float4 v = ((const float4*)in)[i];
  ushort4 o;
  o.x = f2b(v.x); o.y = f2b(v.y); o.z = f2b(v.z); o.w = f2b(v.w);
  ((ushort4*)out)[i] = o;
}

// ---------------- encoder: x_sq = bf16(sq_x @ lin_W^T + lin_b + movie_emb) ----------------
// 2 waves per block, K-split: wave w covers K in [w*384, w*384+384).
// Wave 1 stores fp32 partials to LDS; wave 0 combines + epilogue.
// A-loads have a 1-iteration prefetch to keep HBM requests in flight.
__global__ __launch_bounds__(128) void encoder_mfma(
    const float* __restrict__ A, const ushort* __restrict__ Wb,
    const float* __restrict__ bias, const float* __restrict__ memb,
    ushort* __restrict__ C)
{
  __shared__ float part[16 * 128];   // 8 KB fp32 partial from wave 1
  int tid = threadIdx.x, wave = tid >> 6, lane = tid & 63;
  int rowbase = blockIdx.x * 16;     // 50000 % 16 == 0
  int t = lane >> 4, fr = lane & 15;
  f32x4 acc[8];
  #pragma unroll
  for (int c = 0; c < 8; ++c)
    #pragma unroll
    for (int q = 0; q < 4; ++q) acc[c][q] = 0.f;

  int arow = rowbase + fr;
  int kbase = wave * (FIN / 2);
  const float* Abase = A + (long)arow * FIN + kbase + t * 8;
  const ushort* Wbase = Wb + kbase + t * 8;

  // prefetch first A fragment
  float4 p0 = *(const float4*)Abase;
  float4 p1 = *(const float4*)(Abase + 4);

  for (int ki = 0; ki < FIN / 2 / 32; ++ki) {
    int k0 = ki * 32;
    float4 c0 = p0, c1 = p1;
    if (ki + 1 < FIN / 2 / 32) {
      p0 = *(const float4*)(Abase + k0 + 32);
      p1 = *(const float4*)(Abase + k0 + 36);
    }
    ushort tmp[8];
    tmp[0] = f2b(c0.x); tmp[1] = f2b(c0.y); tmp[2] = f2b(c0.z); tmp[3] = f2b(c0.w);
    tmp[4] = f2b(c1.x); tmp[5] = f2b(c1.y); tmp[6] = f2b(c1.z); tmp[7] = f2b(c1.w);
    bf16x8 af = *(bf16x8*)tmp;
    bf16x8 bfm[8];
    #pragma unroll
    for (int cc = 0; cc < 8; ++cc) {
      int col = cc * 16 + fr;
      bfm[cc] = *(const bf16x8*)(Wbase + (long)col * FIN + k0);
    }
    #pragma unroll
    for (int cc = 0; cc < 8; ++cc)
      acc[cc] = __builtin_amdgcn_mfma_f32_16x16x32_bf16(af, bfm[cc], acc[cc], 0, 0, 0);
  }

  if (wave == 1) {
    #pragma unroll
    for (int cc = 0; cc < 8; ++cc)
      #pragma unroll
      for (int q = 0; q < 4; ++q)
        part[(t * 4 + q) * 128 + cc * 16 + fr] = acc[cc][q];
  }
  __syncthreads();
  if (wave == 0) {
    #pragma unroll
    for (int cc = 0; cc < 8; ++cc)
      #pragma unroll
      for (int q = 0; q < 4; ++q) {
        int row = rowbase + t * 4 + q;
        int col = cc * 16 + fr;
        float v = acc[cc][q] + part[(t * 4 + q) * 128 + col] + bias[col]
                + memb[(long)row * H + col];
        C[(long)row * H + col] = f2b(v);
      }
  }
}

// ---------------- fused SpMM-mean + SAGE GEMM ----------------
// 2 waves per block. Phase 1: wave w means rows [8w, 8w+8) -> shared mtile.
// Barrier. Phase 2: wave w computes output cols [64w, 64w+64).
__global__ __launch_bounds__(128) void fused_layer(
    const ushort* __restrict__ xg,    // gather source (other node type) bf16
    const ushort* __restrict__ xs,    // self features [M, H] bf16
    const int* __restrict__ offs, const int* __restrict__ csr,
    const ushort* __restrict__ Wl, const ushort* __restrict__ Wr,
    const float* __restrict__ bias,
    ushort* __restrict__ Cout, int M, int relu)
{
  __shared__ ushort mtile[16 * 128];  // 4 KB, 16B-slot XOR swizzle
  int tid = threadIdx.x, wave = tid >> 6, lane = tid & 63;
  int rowbase = blockIdx.x * 16;      // M % 16 == 0
  const unsigned* X = (const unsigned*)xg;

  // ---- phase 1: means (8 rows per wave) ----
  int wslot = lane >> 2;
  unsigned* mt32 = (unsigned*)mtile;
  for (int i8 = 0; i8 < 8; ++i8) {
    int i = wave * 8 + i8;
    int row = rowbase + i;
    int s = offs[row], e = offs[row + 1];
    float a0 = 0.f, a1 = 0.f;
    int j = s;
    for (; j + 8 <= e; j += 8) {
      long i0 = csr[j], i1 = csr[j+1], i2 = csr[j+2], i3 = csr[j+3];
      long i4 = csr[j+4], i5 = csr[j+5], i6 = csr[j+6], i7 = csr[j+7];
      unsigned x0 = X[i0*64+lane], x1 = X[i1*64+lane], x2 = X[i2*64+lane], x3 = X[i3*64+lane];
      unsigned x4 = X[i4*64+lane], x5 = X[i5*64+lane], x6 = X[i6*64+lane], x7 = X[i7*64+lane];
      a0 += b2f((ushort)(x0 & 0xffff)) + b2f((ushort)(x1 & 0xffff))
          + b2f((ushort)(x2 & 0xffff)) + b2f((ushort)(x3 & 0xffff))
          + b2f((ushort)(x4 & 0xffff)) + b2f((ushort)(x5 & 0xffff))
          + b2f((ushort)(x6 & 0xffff)) + b2f((ushort)(x7 & 0xffff));
      a1 += b2f((ushort)(x0 >> 16)) + b2f((ushort)(x1 >> 16))
          + b2f((ushort)(x2 >> 16)) + b2f((ushort)(x3 >> 16))
          + b2f((ushort)(x4 >> 16)) + b2f((ushort)(x5 >> 16))
          + b2f((ushort)(x6 >> 16)) + b2f((ushort)(x7 >> 16));
    }
    if (j + 4 <= e) {
      long i0 = csr[j], i1 = csr[j+1], i2 = csr[j+2], i3 = csr[j+3];
      unsigned x0 = X[i0*64+lane], x1 = X[i1*64+lane], x2 = X[i2*64+lane], x3 = X[i3*64+lane];
      a0 += b2f((ushort)(x0 & 0xffff)) + b2f((ushort)(x1 & 0xffff))
          + b2f((ushort)(x2 & 0xffff)) + b2f((ushort)(x3 & 0xffff));
      a1 += b2f((ushort)(x0 >> 16)) + b2f((ushort)(x1 >> 16))
          + b2f((ushort)(x2 >> 16)) + b2f((ushort)(x3 >> 16));
      j += 4;
    }
    for (; j < e; ++j) {
      unsigned x = X[(long)csr[j] * 64 + lane];
      a0 += b2f((ushort)(x & 0xffff));
      a1 += b2f((ushort)(x >> 16));
    }
    float inv = (e > s) ? 1.f / (float)(e - s) : 0.f;
    a0 *= inv; a1 *= inv;
    int sw = (wslot & 8) | ((wslot & 7) ^ (i & 7));
    mt32[i * 64 + sw * 4 + (lane & 3)] = (unsigned)f2b(a0) | ((unsigned)f2b(a1) << 16);
  }
  __syncthreads();

  // ---- phase 2: GEMM, wave w -> col-tiles [4w, 4w+4) ----
  int t = lane >> 4, fr = lane & 15;
  f32x4 acc[4];
  #pragma unroll
  for (int c = 0; c < 4; ++c)
    #pragma unroll
    for (int q = 0; q < 4; ++q) acc[c][q] = 0.f;

  // mean side (A from LDS), K = 128
  #pragma unroll
  for (int ks = 0; ks < 4; ++ks) {
    int slot = ks * 4 + t;
    int sw = (slot & 8) | ((slot & 7) ^ (fr & 7));
    bf16x8 af = *(const bf16x8*)&mtile[fr * 128 + sw * 8];
    bf16x8 bfm[4];
    #pragma unroll
    for (int cc = 0; cc < 4; ++cc) {
      int col = (wave * 4 + cc) * 16 + fr;
      bfm[cc] = *(const bf16x8*)(Wl + (long)col * H + slot * 8);
    }
    #pragma unroll
    for (int cc = 0; cc < 4; ++cc)
      acc[cc] = __builtin_amdgcn_mfma_f32_16x16x32_bf16(af, bfm[cc], acc[cc], 0, 0, 0);
  }
  // self side (A direct from global), K = 128
  int srow = rowbase + fr;
  #pragma unroll
  for (int ks = 0; ks < 4; ++ks) {
    int slot = ks * 4 + t;
    bf16x8 af = *(const bf16x8*)(xs + (long)srow * H + slot * 8);
    bf16x8 bfm[4];
    #pragma unroll
    for (int cc = 0; cc < 4; ++cc) {
      int col = (wave * 4 + cc) * 16 + fr;
      bfm[cc] = *(const bf16x8*)(Wr + (long)col * H + slot * 8);
    }
    #pragma unroll
    for (int cc = 0; cc < 4; ++cc)
      acc[cc] = __builtin_amdgcn_mfma_f32_16x16x32_bf16(af, bfm[cc], acc[cc], 0, 0, 0);
  }
  // epilogue
  #pragma unroll
  for (int cc = 0; cc < 4; ++cc)
    #pragma unroll
    for (int q = 0; q < 4; ++q) {
      int row = rowbase + t * 4 + q;
      int col = (wave * 4 + cc) * 16 + fr;
      float v = acc[cc][q] + bias[col];
      if (relu) v = fmaxf(v, 0.f);
      Cout[(long)row * H + col] = f2b(v);
    }
}

// ---------------- degree count ----------------
__global__ void deg_count(const int* __restrict__ eidx, int* __restrict__ df, int* __restrict__ dr) {
  int e = blockIdx.x * blockDim.x + threadIdx.x;
  if (e >= NE) return;
  atomicAdd(dr + eidx[e], 1);
  atomicAdd(df + eidx[NE + e], 1);
}

// ---------------- dual exclusive scan: block 0 -> forward, block 1 -> reverse ----------------
__global__ __launch_bounds__(1024) void exscan2(
    const int* __restrict__ degf, const int* __restrict__ degr,
    int* __restrict__ offf, int* __restrict__ offr)
{
  __shared__ int part[1024];
  const int* deg = blockIdx.x ? degr : degf;
  int* offs = blockIdx.x ? offr : offf;
  int n = blockIdx.x ? NMQ : NSQ;
  int t = threadIdx.x;
  int chunk = (n + 1023) >> 10;
  int beg = t * chunk, end = beg + chunk;
  if (end > n) end = n;
  int s = 0;
  for (int i = beg; i < end; ++i) s += deg[i];
  part[t] = s;
  __syncthreads();
  for (int offd = 1; offd < 1024; offd <<= 1) {
    int v = 0;
    if (t >= offd) v = part[t - offd];
    __syncthreads();
    part[t] += v;
    __syncthreads();
  }
  int run = (t == 0) ? 0 : part[t - 1];
  for (int i = beg; i < end; ++i) { offs[i] = run; run += deg[i]; }
  if (t == 1023) offs[n] = part[1023];
}

// ---------------- CSR fill ----------------
__global__ void csr_fill(const int* __restrict__ eidx,
                         const int* __restrict__ offs_f, const int* __restrict__ offs_r,
                         int* __restrict__ cur_f, int* __restrict__ cur_r,
                         int* __restrict__ csr_f, int* __restrict__ csr_r) {
  int e = blockIdx.x * blockDim.x + threadIdx.x;
  if (e >= NE) return;
  int s = eidx[e], d = eidx[NE + e];
  int p = atomicAdd(cur_f + d, 1); csr_f[offs_f[d] + p] = s;
  int q = atomicAdd(cur_r + s, 1); csr_r[offs_r[s] + q] = d;
}

// ---------------- classifier: one wave per label edge ----------------
__global__ __launch_bounds__(256) void edge_dot_b(
    const ushort* __restrict__ xmq, const ushort* __restrict__ xsq,
    const int* __restrict__ eli, float* __restrict__ out)
{
  int wid = (blockIdx.x << 2) + (threadIdx.x >> 6);
  int lane = threadIdx.x & 63;
  if (wid >= NEL) return;
  int a = eli[wid], b = eli[NEL + wid];
  unsigned xa = ((const unsigned*)xmq)[(long)a * 64 + lane];
  unsigned xb = ((const unsigned*)xsq)[(long)b * 64 + lane];
  float p = b2f((ushort)(xa & 0xffff)) * b2f((ushort)(xb & 0xffff))
          + b2f((ushort)(xa >> 16))    * b2f((ushort)(xb >> 16));
  #pragma unroll
  for (int off = 32; off; off >>= 1) p += __shfl_down(p, off, 64);
  if (lane == 0) out[wid] = p;
}

extern "C" void kernel_launch(void* const* d_in, const int* in_sizes, int n_in,
                              void* d_out, int out_size, void* d_ws, size_t ws_size,
                              hipStream_t stream) {
  (void)in_sizes; (void)n_in; (void)out_size; (void)ws_size;
  // d_in[0]=mq_node_id (arange, unused), d_in[1]=sq_node_id (arange, unused)
  const float* sq_x      = (const float*)d_in[2];
  const int*   eidx      = (const int*)d_in[3];
  const int*   eli       = (const int*)d_in[4];
  const float* user_emb  = (const float*)d_in[5];
  const float* movie_emb = (const float*)d_in[6];
  const float* lin_W     = (const float*)d_in[7];
  const float* lin_b     = (const float*)d_in[8];
  const float* Wl_s      = (const float*)d_in[9];
  const float* bl_s      = (const float*)d_in[10];
  const float* Wr_s      = (const float*)d_in[11];
  const float* Wl_m      = (const float*)d_in[12];
  const float* bl_m      = (const float*)d_in[13];
  const float* Wr_m      = (const float*)d_in[14];
  float* out = (float*)d_out;

  char* ws = (char*)d_ws;
  size_t off = 0;
  auto alloc = [&](size_t bytes) {
    char* p = ws + off;
    off += (bytes + 255) & ~(size_t)255;
    return p;
  };
  ushort* xmq_a = (ushort*)alloc((size_t)NMQ * H * 2);
  ushort* xmq_b = (ushort*)alloc((size_t)NMQ * H * 2);
  ushort* xsq_a = (ushort*)alloc((size_t)NSQ * H * 2);
  ushort* xsq_b = (ushort*)alloc((size_t)NSQ * H * 2);
  ushort* linWb = (ushort*)alloc((size_t)H * FIN * 2);
  ushort* Wlsb  = (ushort*)alloc((size_t)NLAYERS * H * H * 2);
  ushort* Wrsb  = (ushort*)alloc((size_t)NLAYERS * H * H * 2);
  ushort* Wlmb  = (ushort*)alloc((size_t)NLAYERS * H * H * 2);
  ushort* Wrmb  = (ushort*)alloc((size_t)NLAYERS * H * H * 2);
  int* deg_f  = (int*)alloc((size_t)NSQ * 4);
  int* deg_r  = (int*)alloc((size_t)NMQ * 4);
  int* cur_f  = (int*)alloc((size_t)NSQ * 4);
  int* cur_r  = (int*)alloc((size_t)NMQ * 4);
  int* offs_f = (int*)alloc((size_t)(NSQ + 1) * 4);
  int* offs_r = (int*)alloc((size_t)(NMQ + 1) * 4);
  int* csr_f  = (int*)alloc((size_t)NE * 4);
  int* csr_r  = (int*)alloc((size_t)NE * 4);

  hipMemsetAsync(deg_f, 0, (char*)offs_f - (char*)deg_f, stream);

  // conversions
  cvt_bf16<<<(NMQ * H / 4 + 255) / 256, 256, 0, stream>>>(user_emb, xmq_a, NMQ * H / 4);
  cvt_bf16<<<(H * FIN / 4 + 255) / 256, 256, 0, stream>>>(lin_W, linWb, H * FIN / 4);
  cvt_bf16<<<(NLAYERS * H * H / 4 + 255) / 256, 256, 0, stream>>>(Wl_s, Wlsb, NLAYERS * H * H / 4);
  cvt_bf16<<<(NLAYERS * H * H / 4 + 255) / 256, 256, 0, stream>>>(Wr_s, Wrsb, NLAYERS * H * H / 4);
  cvt_bf16<<<(NLAYERS * H * H / 4 + 255) / 256, 256, 0, stream>>>(Wl_m, Wlmb, NLAYERS * H * H / 4);
  cvt_bf16<<<(NLAYERS * H * H / 4 + 255) / 256, 256, 0, stream>>>(Wr_m, Wrmb, NLAYERS * H * H / 4);

  encoder_mfma<<<NSQ / 16, 128, 0, stream>>>(sq_x, linWb, lin_b, movie_emb, xsq_a);
  deg_count<<<(NE + 255) / 256, 256, 0, stream>>>(eidx, deg_f, deg_r);
  exscan2<<<2, 1024, 0, stream>>>(deg_f, deg_r, offs_f, offs_r);
  csr_fill<<<(NE + 255) / 256, 256, 0, stream>>>(eidx, offs_f, offs_r, cur_f, cur_r, csr_f, csr_r);

  ushort *cm = xmq_a, *cs = xsq_a, *nm = xmq_b, *ns = xsq_b;
  for (int l = 0; l < NLAYERS; ++l) {
    fused_layer<<<NSQ / 16, 128, 0, stream>>>(cm, cs, offs_f, csr_f,
        Wlsb + (size_t)l * H * H, Wrsb + (size_t)l * H * H, bl_s + (size_t)l * H,
        ns, NSQ, l == 0);
    fused_layer<<<NMQ / 16, 128, 0, stream>>>(cs, cm, offs_r, csr_r,
        Wlmb + (size_t)l * H * H, Wrmb + (size_t)l * H * H, bl_m + (size_t)l * H,
        nm, NMQ, l == 0);
    ushort* t;
    t = cm; cm = nm; nm = t;
    t = cs; cs = ns; ns = t;
  }
  edge_dot_b<<<(NEL + 3) / 4, 256, 0, stream>>>(cm, cs, eli, out);
}